// Round 10
// baseline (215.129 us; speedup 1.0000x reference)
//
#include <hip/hip_runtime.h>
#include <hip/hip_fp16.h>

// GCN tail: 2×(GCNConv+ReLU) + linear head.  N=100000, E=1000000, F_in=128, H=64, C=40.
//
// R19: attack the measured fill_gemm1 41us (FETCH 30MB @ 1.2TB/s = dirty-L3
// eviction throttle after the harness's 268MB poison fill) + W-staging.
//  - Non-temporal loads for single-use streams: x (gemm1) and src (fill) via
//    __builtin_nontemporal_load -> no L2/L3 allocation -> no per-fetch dirty
//    eviction. adj in gathers also NT (stops 4MB stream polluting the 4MB L2
//    that caches the h-row table).
//  - 2-tile GEMM blocks: one W staging per 256 rows (was 128). Grids: D1 =
//    123+391=514 blocks, gemm2/head = 391 blocks. Math/MFMA order unchanged.
//  - Pipeline unchanged: {fill||gemm1}, sort, gather1, gemm2, gather2, head.

#define BUCKET_BITS  8
#define BUCKET_NODES 256
#define CAP  8192           // slots per bucket window
#define SLOT 64             // slots per (fill-block, bucket) run; 123*64=7872<=CAP
#define OFF_MASK 0x3FFFFF   // 22 bits
#define CHUNK 8192          // edges per fill block

typedef _Float16 half8 __attribute__((ext_vector_type(8)));
typedef float    f32x4 __attribute__((ext_vector_type(4)));
typedef float    f32x4v __attribute__((ext_vector_type(4)));

union H8  { uint4 u; __half h[8]; };
union HV8 { uint4 u; half8 h; };

// ---- combined: bucket_fill (blocks < EB) || gemm1 (blocks >= EB) -----------
// fill: LDS radix-partition -> run-granular writes to FIXED slots (no atomics).
// gemm1: bufA = x @ W1 (fp16, UNSCALED); 512 thr, 2 tiles x 128 rows per block.
__global__ __launch_bounds__(512) void fill_gemm1_kernel(
    const int* __restrict__ src, const int* __restrict__ dst,
    unsigned int* __restrict__ cntMat, unsigned int* __restrict__ bucketArr,
    const float* __restrict__ x, const float* __restrict__ W1,
    __half* __restrict__ bufA, int N, int E, int NB, int EB) {
    __shared__ __align__(16) char smem[38912];

    if ((int)blockIdx.x < EB) {
        // ---------------- fill ----------------
        unsigned int* ent = (unsigned int*)smem;          // 8192 entries, 32KB
        int* scn  = (int*)(smem + 32768);                 // [512]
        int* cl   = scn + 512;                            // [512]
        int* lcur = cl + 512;                             // [512]
        const int t = threadIdx.x;
        lcur[t] = 0;
        __syncthreads();

        const int base  = blockIdx.x * CHUNK;
        const int count = min(CHUNK, E - base);

        for (int i = t; i < count; i += 512)
            atomicAdd(&lcur[dst[base + i] >> BUCKET_BITS], 1);
        __syncthreads();

        int c = lcur[t];
        cl[t]  = c;
        scn[t] = c;
        __syncthreads();
        for (int off = 1; off < 512; off <<= 1) {
            int a = (t >= off) ? scn[t - off] : 0;
            __syncthreads();
            scn[t] += a;
            __syncthreads();
        }

        if (t < NB) cntMat[t * 128 + blockIdx.x] = (unsigned)min(c, SLOT);
        lcur[t] = scn[t] - c;                 // runStart (local cursor)
        __syncthreads();

        for (int i = t; i < count; i += 512) {
            const int d = dst[base + i];
            const int s = __builtin_nontemporal_load(src + base + i);  // NT: read-once stream
            const int b = d >> BUCKET_BITS;
            const int p = atomicAdd(&lcur[b], 1);
            ent[p] = ((unsigned)(d & (BUCKET_NODES - 1)) << 24) | (unsigned)s;
        }
        __syncthreads();

        for (int j = t; j < count; j += 512) {
            int lo = 0, hi = 511;
            while (lo < hi) {
                int mid = (lo + hi) >> 1;
                if (scn[mid] > j) hi = mid; else lo = mid + 1;
            }
            const int off = j - (scn[lo] - cl[lo]);
            if (off < SLOT)
                bucketArr[lo * CAP + blockIdx.x * SLOT + off] = ent[j];
        }
    } else {
        // ------- gemm1: 2 tiles x (8 waves x 16 rows = 128 rows) -------
        constexpr int K = 128, KP = 136, NCT = 4;
        _Float16* WTh = (_Float16*)smem;
        _Float16* WTl = WTh + 64 * KP;

        for (int i = threadIdx.x; i < K * 64; i += 512) {
            int k = i >> 6, cc = i & 63;
            float w = W1[k * 64 + cc];
            _Float16 h = (_Float16)w;
            WTh[cc * KP + k] = h;
            WTl[cc * KP + k] = (_Float16)(w - (float)h);
        }
        __syncthreads();

        const int lane = threadIdx.x & 63;
        const int wv   = threadIdx.x >> 6;          // 0..7
        const int r    = lane & 15;
        const int q    = lane >> 4;
        const int p    = blockIdx.x - EB;           // tile-pair index

#pragma unroll
        for (int tt = 0; tt < 2; ++tt) {
            const int rowbase = p * 256 + tt * 128;
            int arow = rowbase + wv * 16 + r;
            if (arow > N - 1) arow = N - 1;

            f32x4 acc[NCT] = {};
#pragma unroll
            for (int kst = 0; kst < K; kst += 32) {
                half8 ah, al;
                const float* ap = x + (size_t)arow * K + kst + q * 8;
                f32x4v f0 = __builtin_nontemporal_load((const f32x4v*)ap);       // NT: x read once
                f32x4v f1 = __builtin_nontemporal_load((const f32x4v*)(ap + 4)); // NT
                float fs[8] = {f0[0], f0[1], f0[2], f0[3], f1[0], f1[1], f1[2], f1[3]};
#pragma unroll
                for (int j = 0; j < 8; ++j) {
                    _Float16 h = (_Float16)fs[j];
                    ah[j] = h;
                    al[j] = (_Float16)(fs[j] - (float)h);
                }
#pragma unroll
                for (int n = 0; n < NCT; ++n) {
                    const int bo = (n * 16 + r) * KP + kst + q * 8;
                    HV8 bh, bl;
                    bh.u = *(const uint4*)(WTh + bo);
                    bl.u = *(const uint4*)(WTl + bo);
                    acc[n] = __builtin_amdgcn_mfma_f32_16x16x32_f16(ah, bh.h, acc[n], 0, 0, 0);
                    acc[n] = __builtin_amdgcn_mfma_f32_16x16x32_f16(ah, bl.h, acc[n], 0, 0, 0);
                    acc[n] = __builtin_amdgcn_mfma_f32_16x16x32_f16(al, bh.h, acc[n], 0, 0, 0);
                }
            }

            const int orow0 = rowbase + wv * 16 + q * 4;
#pragma unroll
            for (int n = 0; n < NCT; ++n) {
                const int col = n * 16 + r;
#pragma unroll
                for (int j = 0; j < 4; ++j) {
                    const int row = orow0 + j;
                    if (row >= N) break;
                    bufA[(size_t)row * 64 + col] = __float2half(acc[n][j]);
                }
            }
        }
    }
}

// ---- node_sort v3: gather runs via cntMat, no global cursor ----------------
__global__ __launch_bounds__(512) void node_sort_kernel(
    const unsigned int* __restrict__ cntMat, const unsigned int* __restrict__ bucketArr,
    unsigned int* __restrict__ nodeInfo, float* __restrict__ dinv,
    unsigned int* __restrict__ adj, int N, int EB) {
    __shared__ unsigned int win[CAP];     // 32 KB compacted window
    __shared__ int cnt[BUCKET_NODES];
    __shared__ int scn[BUCKET_NODES];
    __shared__ int cur[BUCKET_NODES];
    __shared__ int rc[128];
    __shared__ int rs[128];
    const int t = threadIdx.x;
    const int b = blockIdx.x;
    if (t < BUCKET_NODES) cnt[t] = 0;
    if (t < 128) rc[t] = (t < EB) ? (int)cntMat[b * 128 + t] : 0;
    __syncthreads();

    if (t < 128) rs[t] = rc[t];
    __syncthreads();
    for (int off = 1; off < 128; off <<= 1) {
        int a = 0;
        if (t < 128 && t >= off) a = rs[t - off];
        __syncthreads();
        if (t < 128) rs[t] += a;
        __syncthreads();
    }
    const int total = rs[127];

    for (int idx = t; idx < EB * SLOT; idx += 512) {
        const int eb  = idx >> 6;
        const int off = idx & (SLOT - 1);
        if (off < rc[eb]) {
            const unsigned e = bucketArr[b * CAP + idx];
            win[rs[eb] - rc[eb] + off] = e;
            atomicAdd(&cnt[e >> 24], 1);
        }
    }
    __syncthreads();

    if (t < BUCKET_NODES) scn[t] = cnt[t];
    __syncthreads();
    for (int off = 1; off < BUCKET_NODES; off <<= 1) {
        int a = 0;
        if (t < BUCKET_NODES && t >= off) a = scn[t - off];
        __syncthreads();
        if (t < BUCKET_NODES) scn[t] += a;
        __syncthreads();
    }
    if (t < BUCKET_NODES) {
        const int v    = cnt[t];
        const int excl = scn[t] - v;
        const int node = b * BUCKET_NODES + t;
        if (node < N) {
            nodeInfo[node] = ((unsigned)v << 22) | (unsigned)(b * CAP + excl);
            dinv[node]     = rsqrtf((float)(v + 1));
        }
        cur[t] = excl;
    }
    __syncthreads();

    for (int i = t; i < total; i += 512) {
        const unsigned entry = win[i];
        const int p = atomicAdd(&cur[entry >> 24], 1);
        adj[b * CAP + p] = entry & 0xFFFFFF;
    }
}

// ---- MFMA GEMM (gemm2 / head): 2 tiles x 128 rows per block ----------------
template <int NOUT, int NCT, bool OHALF, bool SCALE, bool BIAS>
__global__ __launch_bounds__(512) void gemm_mfma(const __half* __restrict__ Ah,
                                                 const float* __restrict__ W,
                                                 const float* __restrict__ bias,
                                                 const float* __restrict__ dscale,
                                                 void* __restrict__ outv, int M) {
    constexpr int K = 64, KP = 72;
    __shared__ _Float16 WTh[64 * KP];
    __shared__ _Float16 WTl[64 * KP];

    for (int i = threadIdx.x; i < K * 64; i += 512) {
        int k = i >> 6, c = i & 63;
        float w = (NOUT == 64 || c < NOUT) ? W[k * NOUT + c] : 0.f;
        _Float16 h = (_Float16)w;
        WTh[c * KP + k] = h;
        WTl[c * KP + k] = (_Float16)(w - (float)h);
    }
    __syncthreads();

    const int lane = threadIdx.x & 63;
    const int wv   = threadIdx.x >> 6;          // 0..7
    const int r    = lane & 15;
    const int q    = lane >> 4;

#pragma unroll
    for (int tt = 0; tt < 2; ++tt) {
        const int rowbase = blockIdx.x * 256 + tt * 128;
        int arow = rowbase + wv * 16 + r;
        if (arow > M - 1) arow = M - 1;

        f32x4 acc[NCT] = {};
#pragma unroll
        for (int kst = 0; kst < K; kst += 32) {
            HV8 v;
            v.u = *(const uint4*)(Ah + (size_t)arow * K + kst + q * 8);
#pragma unroll
            for (int n = 0; n < NCT; ++n) {
                const int bo = (n * 16 + r) * KP + kst + q * 8;
                HV8 bh, bl;
                bh.u = *(const uint4*)(WTh + bo);
                bl.u = *(const uint4*)(WTl + bo);
                acc[n] = __builtin_amdgcn_mfma_f32_16x16x32_f16(v.h, bh.h, acc[n], 0, 0, 0);
                acc[n] = __builtin_amdgcn_mfma_f32_16x16x32_f16(v.h, bl.h, acc[n], 0, 0, 0);
            }
        }

        const int orow0 = rowbase + wv * 16 + q * 4;
#pragma unroll
        for (int n = 0; n < NCT; ++n) {
            const int col = n * 16 + r;
            float bb = 0.f;
            if (BIAS) bb = (col < NOUT) ? bias[col] : 0.f;
#pragma unroll
            for (int j = 0; j < 4; ++j) {
                const int row = orow0 + j;
                if (row >= M) break;
                const float sc = SCALE ? dscale[row] : 1.f;
                const float v2 = acc[n][j] * sc + bb;
                if (OHALF) {
                    ((__half*)outv)[(size_t)row * NOUT + col] = __float2half(v2);
                } else if (col < NOUT) {
                    ((float*)outv)[(size_t)row * NOUT + col] = v2;
                }
            }
        }
    }
}

// ---- gather: eighth-wave; NBRSCALE=true applies dinv[s] per neighbor -------
// adj loads NT (read-once stream; keeps h-row table unpolluted in L2).
template <bool NBRSCALE>
__global__ __launch_bounds__(256) void gather_kernel(const __half* __restrict__ h,
                                                     const unsigned int* __restrict__ nodeInfo,
                                                     const unsigned int* __restrict__ adj,
                                                     const float* __restrict__ dinv,
                                                     const float* __restrict__ bias,
                                                     __half* __restrict__ out, int N) {
    const int node = blockIdx.x * 32 + (threadIdx.x >> 3);
    const int l    = threadIdx.x & 7;
    if (node >= N) return;

    const unsigned info = nodeInfo[node];
    const int start = (int)(info & OFF_MASK);
    const int end   = start + (int)(info >> 22);
    const float di  = dinv[node];

    float acc[8];
    {
        H8 sv;
        sv.u = *(const uint4*)(h + (size_t)node * 64 + l * 8);
        const float self = NBRSCALE ? di : 1.f;
#pragma unroll
        for (int k = 0; k < 8; ++k) acc[k] = __half2float(sv.h[k]) * self;
    }

    for (int base = start; ; base += 8) {
        bool active = base < end;
        if (__ballot(active) == 0ull) break;
        const int m = active ? min(8, end - base) : 0;

        int s[8];
#pragma unroll
        for (int j = 0; j < 8; ++j)
            s[j] = (int)__builtin_nontemporal_load(adj + base + j);   // NT stream

        float dv[8];
        if (NBRSCALE) {
#pragma unroll
            for (int j = 0; j < 8; ++j) dv[j] = (j < m) ? dinv[s[j]] : 0.f;
        }

        uint4 rv[8];
#pragma unroll
        for (int j = 0; j < 8; ++j)
            if (j < m) rv[j] = *(const uint4*)(h + (size_t)s[j] * 64 + l * 8);

#pragma unroll
        for (int j = 0; j < 8; ++j)
            if (j < m) {
                H8 tt;
                tt.u = rv[j];
                const float w = NBRSCALE ? dv[j] : 1.f;
#pragma unroll
                for (int k = 0; k < 8; ++k) acc[k] += __half2float(tt.h[k]) * w;
            }
    }

    const float4 b0 = *(const float4*)(bias + l * 8);
    const float4 b1 = *(const float4*)(bias + l * 8 + 4);
    const float bb[8] = {b0.x, b0.y, b0.z, b0.w, b1.x, b1.y, b1.z, b1.w};
    H8 ov;
#pragma unroll
    for (int k = 0; k < 8; ++k) {
        float v = acc[k] * di + bb[k];
        ov.h[k] = __float2half(v > 0.f ? v : 0.f);
    }
    *(uint4*)(out + (size_t)node * 64 + l * 8) = ov.u;
}

extern "C" void kernel_launch(void* const* d_in, const int* in_sizes, int n_in,
                              void* d_out, int out_size, void* d_ws, size_t ws_size,
                              hipStream_t stream) {
    const float* x  = (const float*)d_in[0];
    const int*   ei = (const int*)d_in[1];
    const float* W1 = (const float*)d_in[2];
    const float* b1 = (const float*)d_in[3];
    const float* W2 = (const float*)d_in[4];
    const float* b2 = (const float*)d_in[5];
    const float* Wc = (const float*)d_in[6];
    const float* bc = (const float*)d_in[7];

    const int N = in_sizes[0] / 128;   // 100000
    const int E = in_sizes[1] / 2;     // 1000000
    const int* src = ei;
    const int* dst = ei + E;

    const int NB = (N + BUCKET_NODES - 1) >> BUCKET_BITS;   // 391
    const int EB = (E + CHUNK - 1) / CHUNK;                  // 123

    char* w = (char*)d_ws;
    auto alloc = [&](size_t bytes) { char* p = w; w += (bytes + 255) & ~(size_t)255; return p; };
    unsigned int* cntMat    = (unsigned int*)alloc((size_t)NB * 128 * 4);
    unsigned int* bucketArr = (unsigned int*)alloc((size_t)NB * CAP * 4);
    unsigned int* nodeInfo  = (unsigned int*)alloc((size_t)N * 4);
    unsigned int* adj       = (unsigned int*)alloc((size_t)NB * CAP * 4);
    float*        dinv      = (float*)alloc((size_t)N * 4);
    __half*       bufA      = (__half*)alloc((size_t)N * 64 * 2);
    __half*       bufB      = (__half*)alloc((size_t)N * 64 * 2);
    __half*       bufC      = (__half*)alloc((size_t)N * 64 * 2);
    __half*       bufD      = (__half*)alloc((size_t)N * 64 * 2);

    const int nblkP = (N + 255) / 256;    // 391 tile-pairs (256 rows/block)
    const int nblkV = (N + 31) / 32;      // 3125

    // 1) fill || gemm1 (123 + 391 = 514 blocks -> fully co-resident)
    fill_gemm1_kernel<<<EB + nblkP, dim3(512), 0, stream>>>(
        src, dst, cntMat, bucketArr, x, W1, bufA, N, E, NB, EB);

    // 2) sort
    node_sort_kernel<<<NB, dim3(512), 0, stream>>>(
        cntMat, bucketArr, nodeInfo, dinv, adj, N, EB);

    // 3) gather1 with per-neighbor dinv (bufA unscaled)
    gather_kernel<true><<<nblkV, dim3(256), 0, stream>>>(bufA, nodeInfo, adj, dinv, b1, bufB, N);

    // 4) gemm2: bufC = (bufB @ W2) * dinv
    gemm_mfma<64, 4, true, true, false><<<nblkP, dim3(512), 0, stream>>>(
        bufB, W2, nullptr, dinv, bufC, N);

    // 5) gather2 (pre-scaled form)
    gather_kernel<false><<<nblkV, dim3(256), 0, stream>>>(bufC, nodeInfo, adj, dinv, b2, bufD, N);

    // 6) head
    gemm_mfma<40, 3, false, false, true><<<nblkP, dim3(512), 0, stream>>>(
        bufD, Wc, bc, nullptr, d_out, N);
}

// Round 11
// 209.693 us; speedup vs baseline: 1.0259x; 1.0259x over previous
//
#include <hip/hip_runtime.h>
#include <hip/hip_fp16.h>

// GCN tail: 2×(GCNConv+ReLU) + linear head.  N=100000, E=1000000, F_in=128, H=64, C=40.
//
// R20: revert R19 (NT loads + 2-tile: -12us regression; NT adj re-fetch
// amplification). Bodies are exact R18 (best verified 203.1us). One schedule
// change: dependency-optimal dispatch split.
//   D1 = fill alone (sort's only dependency)
//   D2 = {sort || gemm1} block-range split (mutually independent)
//   D3..D6 = gather1, gemm2, gather2, head (unchanged)
// Critical path: fill + max(sort,gemm1) + ... instead of
// max(fill,gemm1) + sort + ...  -> sort rides inside gemm1's window.

#define BUCKET_BITS  8
#define BUCKET_NODES 256
#define CAP  8192           // slots per bucket window
#define SLOT 64             // slots per (fill-block, bucket) run; 123*64=7872<=CAP
#define OFF_MASK 0x3FFFFF   // 22 bits
#define CHUNK 8192          // edges per fill block

typedef _Float16 half8 __attribute__((ext_vector_type(8)));
typedef float    f32x4 __attribute__((ext_vector_type(4)));

union H8  { uint4 u; __half h[8]; };
union HV8 { uint4 u; half8 h; };

// ---- D1: bucket_fill (LDS radix-partition, fixed slots, no global atomics) --
__global__ __launch_bounds__(512) void fill_kernel(
    const int* __restrict__ src, const int* __restrict__ dst,
    unsigned int* __restrict__ cntMat, unsigned int* __restrict__ bucketArr,
    int E, int NB) {
    __shared__ __align__(16) char smem[38912];
    unsigned int* ent = (unsigned int*)smem;          // 8192 entries, 32KB
    int* scn  = (int*)(smem + 32768);                 // [512]
    int* cl   = scn + 512;                            // [512]
    int* lcur = cl + 512;                             // [512]
    const int t = threadIdx.x;
    lcur[t] = 0;
    __syncthreads();

    const int base  = blockIdx.x * CHUNK;
    const int count = min(CHUNK, E - base);

    for (int i = t; i < count; i += 512)
        atomicAdd(&lcur[dst[base + i] >> BUCKET_BITS], 1);
    __syncthreads();

    int c = lcur[t];
    cl[t]  = c;
    scn[t] = c;
    __syncthreads();
    for (int off = 1; off < 512; off <<= 1) {
        int a = (t >= off) ? scn[t - off] : 0;
        __syncthreads();
        scn[t] += a;
        __syncthreads();
    }

    if (t < NB) cntMat[t * 128 + blockIdx.x] = (unsigned)min(c, SLOT);
    lcur[t] = scn[t] - c;                 // runStart (local cursor)
    __syncthreads();

    for (int i = t; i < count; i += 512) {
        const int d = dst[base + i];
        const int s = src[base + i];
        const int b = d >> BUCKET_BITS;
        const int p = atomicAdd(&lcur[b], 1);
        ent[p] = ((unsigned)(d & (BUCKET_NODES - 1)) << 24) | (unsigned)s;
    }
    __syncthreads();

    for (int j = t; j < count; j += 512) {
        int lo = 0, hi = 511;
        while (lo < hi) {
            int mid = (lo + hi) >> 1;
            if (scn[mid] > j) hi = mid; else lo = mid + 1;
        }
        const int off = j - (scn[lo] - cl[lo]);
        if (off < SLOT)
            bucketArr[lo * CAP + blockIdx.x * SLOT + off] = ent[j];
    }
}

// ---- D2: node_sort (blocks < NB) || gemm1 (blocks >= NB) -------------------
// sort: compact runs -> adj + nodeInfo + dinv (depends only on fill).
// gemm1: bufA = x @ W1 (fp16, UNSCALED; dinv applied in gather1) — depends on
// nothing. 8 waves x 16 rows = 128 rows/block.
__global__ __launch_bounds__(512) void sort_gemm1_kernel(
    const unsigned int* __restrict__ cntMat, const unsigned int* __restrict__ bucketArr,
    unsigned int* __restrict__ nodeInfo, float* __restrict__ dinv,
    unsigned int* __restrict__ adj,
    const float* __restrict__ x, const float* __restrict__ W1,
    __half* __restrict__ bufA, int N, int NB, int EB) {
    __shared__ __align__(16) char smem[38912];

    if ((int)blockIdx.x < NB) {
        // ---------------- node_sort ----------------
        unsigned int* win = (unsigned int*)smem;          // CAP entries, 32KB
        int* cnt = (int*)(smem + 32768);                  // [256]
        int* scn = cnt + 256;                             // [256]
        int* cur = scn + 256;                             // [256]
        int* rc  = cur + 256;                             // [128]
        int* rs  = rc + 128;                              // [128]
        const int t = threadIdx.x;
        const int b = blockIdx.x;
        if (t < BUCKET_NODES) cnt[t] = 0;
        if (t < 128) rc[t] = (t < EB) ? (int)cntMat[b * 128 + t] : 0;
        __syncthreads();

        if (t < 128) rs[t] = rc[t];
        __syncthreads();
        for (int off = 1; off < 128; off <<= 1) {
            int a = 0;
            if (t < 128 && t >= off) a = rs[t - off];
            __syncthreads();
            if (t < 128) rs[t] += a;
            __syncthreads();
        }
        const int total = rs[127];

        for (int idx = t; idx < EB * SLOT; idx += 512) {
            const int eb  = idx >> 6;
            const int off = idx & (SLOT - 1);
            if (off < rc[eb]) {
                const unsigned e = bucketArr[b * CAP + idx];
                win[rs[eb] - rc[eb] + off] = e;
                atomicAdd(&cnt[e >> 24], 1);
            }
        }
        __syncthreads();

        if (t < BUCKET_NODES) scn[t] = cnt[t];
        __syncthreads();
        for (int off = 1; off < BUCKET_NODES; off <<= 1) {
            int a = 0;
            if (t < BUCKET_NODES && t >= off) a = scn[t - off];
            __syncthreads();
            if (t < BUCKET_NODES) scn[t] += a;
            __syncthreads();
        }
        if (t < BUCKET_NODES) {
            const int v    = cnt[t];
            const int excl = scn[t] - v;
            const int node = b * BUCKET_NODES + t;
            if (node < N) {
                nodeInfo[node] = ((unsigned)v << 22) | (unsigned)(b * CAP + excl);
                dinv[node]     = rsqrtf((float)(v + 1));
            }
            cur[t] = excl;
        }
        __syncthreads();

        for (int i = t; i < total; i += 512) {
            const unsigned entry = win[i];
            const int p = atomicAdd(&cur[entry >> 24], 1);
            adj[b * CAP + p] = entry & 0xFFFFFF;
        }
    } else {
        // ---------------- gemm1: 8 waves x 16 rows = 128 rows ----------------
        constexpr int K = 128, KP = 136, NCT = 4;
        _Float16* WTh = (_Float16*)smem;
        _Float16* WTl = WTh + 64 * KP;

        for (int i = threadIdx.x; i < K * 64; i += 512) {
            int k = i >> 6, cc = i & 63;
            float w = W1[k * 64 + cc];
            _Float16 h = (_Float16)w;
            WTh[cc * KP + k] = h;
            WTl[cc * KP + k] = (_Float16)(w - (float)h);
        }
        __syncthreads();

        const int lane = threadIdx.x & 63;
        const int wv   = threadIdx.x >> 6;          // 0..7
        const int r    = lane & 15;
        const int q    = lane >> 4;
        const int tile = blockIdx.x - NB;
        int arow = tile * 128 + wv * 16 + r;
        if (arow > N - 1) arow = N - 1;

        f32x4 acc[NCT] = {};
#pragma unroll
        for (int kst = 0; kst < K; kst += 32) {
            half8 ah, al;
            const float* ap = x + (size_t)arow * K + kst + q * 8;
            float4 f0 = *(const float4*)ap;
            float4 f1 = *(const float4*)(ap + 4);
            float fs[8] = {f0.x, f0.y, f0.z, f0.w, f1.x, f1.y, f1.z, f1.w};
#pragma unroll
            for (int j = 0; j < 8; ++j) {
                _Float16 h = (_Float16)fs[j];
                ah[j] = h;
                al[j] = (_Float16)(fs[j] - (float)h);
            }
#pragma unroll
            for (int n = 0; n < NCT; ++n) {
                const int bo = (n * 16 + r) * KP + kst + q * 8;
                HV8 bh, bl;
                bh.u = *(const uint4*)(WTh + bo);
                bl.u = *(const uint4*)(WTl + bo);
                acc[n] = __builtin_amdgcn_mfma_f32_16x16x32_f16(ah, bh.h, acc[n], 0, 0, 0);
                acc[n] = __builtin_amdgcn_mfma_f32_16x16x32_f16(ah, bl.h, acc[n], 0, 0, 0);
                acc[n] = __builtin_amdgcn_mfma_f32_16x16x32_f16(al, bh.h, acc[n], 0, 0, 0);
            }
        }

        const int orow0 = tile * 128 + wv * 16 + q * 4;
#pragma unroll
        for (int n = 0; n < NCT; ++n) {
            const int col = n * 16 + r;
#pragma unroll
            for (int j = 0; j < 4; ++j) {
                const int row = orow0 + j;
                if (row >= N) break;
                bufA[(size_t)row * 64 + col] = __float2half(acc[n][j]);
            }
        }
    }
}

// ---- MFMA GEMM (gemm2 / head): 512 threads = 8 waves x 16 rows = 128 rows --
template <int NOUT, int NCT, bool OHALF, bool SCALE, bool BIAS>
__global__ __launch_bounds__(512) void gemm_mfma(const __half* __restrict__ Ah,
                                                 const float* __restrict__ W,
                                                 const float* __restrict__ bias,
                                                 const float* __restrict__ dscale,
                                                 void* __restrict__ outv, int M) {
    constexpr int K = 64, KP = 72;
    __shared__ _Float16 WTh[64 * KP];
    __shared__ _Float16 WTl[64 * KP];

    for (int i = threadIdx.x; i < K * 64; i += 512) {
        int k = i >> 6, c = i & 63;
        float w = (NOUT == 64 || c < NOUT) ? W[k * NOUT + c] : 0.f;
        _Float16 h = (_Float16)w;
        WTh[c * KP + k] = h;
        WTl[c * KP + k] = (_Float16)(w - (float)h);
    }
    __syncthreads();

    const int lane = threadIdx.x & 63;
    const int wv   = threadIdx.x >> 6;          // 0..7
    const int r    = lane & 15;
    const int q    = lane >> 4;
    int arow = blockIdx.x * 128 + wv * 16 + r;
    if (arow > M - 1) arow = M - 1;

    f32x4 acc[NCT] = {};
#pragma unroll
    for (int kst = 0; kst < K; kst += 32) {
        HV8 v;
        v.u = *(const uint4*)(Ah + (size_t)arow * K + kst + q * 8);
#pragma unroll
        for (int n = 0; n < NCT; ++n) {
            const int bo = (n * 16 + r) * KP + kst + q * 8;
            HV8 bh, bl;
            bh.u = *(const uint4*)(WTh + bo);
            bl.u = *(const uint4*)(WTl + bo);
            acc[n] = __builtin_amdgcn_mfma_f32_16x16x32_f16(v.h, bh.h, acc[n], 0, 0, 0);
            acc[n] = __builtin_amdgcn_mfma_f32_16x16x32_f16(v.h, bl.h, acc[n], 0, 0, 0);
        }
    }

    const int orow0 = blockIdx.x * 128 + wv * 16 + q * 4;
#pragma unroll
    for (int n = 0; n < NCT; ++n) {
        const int col = n * 16 + r;
        float bb = 0.f;
        if (BIAS) bb = (col < NOUT) ? bias[col] : 0.f;
#pragma unroll
        for (int j = 0; j < 4; ++j) {
            const int row = orow0 + j;
            if (row >= M) break;
            const float sc = SCALE ? dscale[row] : 1.f;
            const float v2 = acc[n][j] * sc + bb;
            if (OHALF) {
                ((__half*)outv)[(size_t)row * NOUT + col] = __float2half(v2);
            } else if (col < NOUT) {
                ((float*)outv)[(size_t)row * NOUT + col] = v2;
            }
        }
    }
}

// ---- gather: eighth-wave; NBRSCALE=true applies dinv[s] per neighbor -------
template <bool NBRSCALE>
__global__ __launch_bounds__(256) void gather_kernel(const __half* __restrict__ h,
                                                     const unsigned int* __restrict__ nodeInfo,
                                                     const unsigned int* __restrict__ adj,
                                                     const float* __restrict__ dinv,
                                                     const float* __restrict__ bias,
                                                     __half* __restrict__ out, int N) {
    const int node = blockIdx.x * 32 + (threadIdx.x >> 3);
    const int l    = threadIdx.x & 7;
    if (node >= N) return;

    const unsigned info = nodeInfo[node];
    const int start = (int)(info & OFF_MASK);
    const int end   = start + (int)(info >> 22);
    const float di  = dinv[node];

    float acc[8];
    {
        H8 sv;
        sv.u = *(const uint4*)(h + (size_t)node * 64 + l * 8);
        const float self = NBRSCALE ? di : 1.f;
#pragma unroll
        for (int k = 0; k < 8; ++k) acc[k] = __half2float(sv.h[k]) * self;
    }

    for (int base = start; ; base += 8) {
        bool active = base < end;
        if (__ballot(active) == 0ull) break;
        const int m = active ? min(8, end - base) : 0;

        int s[8];
#pragma unroll
        for (int j = 0; j < 8; ++j) s[j] = (int)adj[base + j];

        float dv[8];
        if (NBRSCALE) {
#pragma unroll
            for (int j = 0; j < 8; ++j) dv[j] = (j < m) ? dinv[s[j]] : 0.f;
        }

        uint4 rv[8];
#pragma unroll
        for (int j = 0; j < 8; ++j)
            if (j < m) rv[j] = *(const uint4*)(h + (size_t)s[j] * 64 + l * 8);

#pragma unroll
        for (int j = 0; j < 8; ++j)
            if (j < m) {
                H8 tt;
                tt.u = rv[j];
                const float w = NBRSCALE ? dv[j] : 1.f;
#pragma unroll
                for (int k = 0; k < 8; ++k) acc[k] += __half2float(tt.h[k]) * w;
            }
    }

    const float4 b0 = *(const float4*)(bias + l * 8);
    const float4 b1 = *(const float4*)(bias + l * 8 + 4);
    const float bb[8] = {b0.x, b0.y, b0.z, b0.w, b1.x, b1.y, b1.z, b1.w};
    H8 ov;
#pragma unroll
    for (int k = 0; k < 8; ++k) {
        float v = acc[k] * di + bb[k];
        ov.h[k] = __float2half(v > 0.f ? v : 0.f);
    }
    *(uint4*)(out + (size_t)node * 64 + l * 8) = ov.u;
}

extern "C" void kernel_launch(void* const* d_in, const int* in_sizes, int n_in,
                              void* d_out, int out_size, void* d_ws, size_t ws_size,
                              hipStream_t stream) {
    const float* x  = (const float*)d_in[0];
    const int*   ei = (const int*)d_in[1];
    const float* W1 = (const float*)d_in[2];
    const float* b1 = (const float*)d_in[3];
    const float* W2 = (const float*)d_in[4];
    const float* b2 = (const float*)d_in[5];
    const float* Wc = (const float*)d_in[6];
    const float* bc = (const float*)d_in[7];

    const int N = in_sizes[0] / 128;   // 100000
    const int E = in_sizes[1] / 2;     // 1000000
    const int* src = ei;
    const int* dst = ei + E;

    const int NB = (N + BUCKET_NODES - 1) >> BUCKET_BITS;   // 391
    const int EB = (E + CHUNK - 1) / CHUNK;                  // 123

    char* w = (char*)d_ws;
    auto alloc = [&](size_t bytes) { char* p = w; w += (bytes + 255) & ~(size_t)255; return p; };
    unsigned int* cntMat    = (unsigned int*)alloc((size_t)NB * 128 * 4);
    unsigned int* bucketArr = (unsigned int*)alloc((size_t)NB * CAP * 4);
    unsigned int* nodeInfo  = (unsigned int*)alloc((size_t)N * 4);
    unsigned int* adj       = (unsigned int*)alloc((size_t)NB * CAP * 4);
    float*        dinv      = (float*)alloc((size_t)N * 4);
    __half*       bufA      = (__half*)alloc((size_t)N * 64 * 2);
    __half*       bufB      = (__half*)alloc((size_t)N * 64 * 2);
    __half*       bufC      = (__half*)alloc((size_t)N * 64 * 2);
    __half*       bufD      = (__half*)alloc((size_t)N * 64 * 2);

    const int nblkG = (N + 127) / 128;    // 782 (128 rows/block)
    const int nblkV = (N + 31) / 32;      // 3125

    // D1: fill (sort's only dependency)
    fill_kernel<<<EB, dim3(512), 0, stream>>>(src, dst, cntMat, bucketArr, E, NB);

    // D2: sort || gemm1 (mutually independent; 391 + 782 = 1173 blocks)
    sort_gemm1_kernel<<<NB + nblkG, dim3(512), 0, stream>>>(
        cntMat, bucketArr, nodeInfo, dinv, adj, x, W1, bufA, N, NB, EB);

    // D3: gather1 with per-neighbor dinv (bufA unscaled)
    gather_kernel<true><<<nblkV, dim3(256), 0, stream>>>(bufA, nodeInfo, adj, dinv, b1, bufB, N);

    // D4: gemm2: bufC = (bufB @ W2) * dinv
    gemm_mfma<64, 4, true, true, false><<<nblkG, dim3(512), 0, stream>>>(
        bufB, W2, nullptr, dinv, bufC, N);

    // D5: gather2 (pre-scaled form)
    gather_kernel<false><<<nblkV, dim3(256), 0, stream>>>(bufC, nodeInfo, adj, dinv, b2, bufD, N);

    // D6: head
    gemm_mfma<40, 3, false, false, true><<<nblkG, dim3(512), 0, stream>>>(
        bufD, Wc, bc, nullptr, d_out, N);
}

// Round 12
// 208.164 us; speedup vs baseline: 1.0335x; 1.0073x over previous
//
#include <hip/hip_runtime.h>
#include <hip/hip_fp16.h>

// GCN tail: 2×(GCNConv+ReLU) + linear head.  N=100000, E=1000000, F_in=128, H=64, C=40.
//
// R21: hybrid schedule of R18 (203.1, best) and R20 (209.7).
//   R18: D1={fill||gemm1 all}, D2=sort  -> sort cost fully exposed.
//   R20: D1=fill, D2={sort||gemm1}      -> first-dispatch window paid on tiny fill.
//   R21: gemm1 split across BOTH:
//     D1 = {fill(123) || gemm1 tiles [0,430)}      (553 blocks, co-resident)
//     D2 = {sort(391) || gemm1 tiles [430,782)}    (743 blocks, co-resident)
//   sort hides under gemm1's second half; fill amortizes the first-dispatch
//   window with gemm1's first half. All bodies bit-identical to R18 ->
//   absmax must stay 0.0078125.
// Pipeline: D1, D2, gather1(nbr-scale), gemm2, gather2, head (6 launches).

#define BUCKET_BITS  8
#define BUCKET_NODES 256
#define CAP  8192           // slots per bucket window
#define SLOT 64             // slots per (fill-block, bucket) run; 123*64=7872<=CAP
#define OFF_MASK 0x3FFFFF   // 22 bits
#define CHUNK 8192          // edges per fill block
#define G1A   430           // gemm1 tiles in D1 (rest go in D2)

typedef _Float16 half8 __attribute__((ext_vector_type(8)));
typedef float    f32x4 __attribute__((ext_vector_type(4)));

union H8  { uint4 u; __half h[8]; };
union HV8 { uint4 u; half8 h; };

// ---- shared gemm1 tile body: bufA[tile*128 ..] = x @ W1 (fp16, unscaled) ----
__device__ __forceinline__ void gemm1_tile(const float* __restrict__ x,
                                           const float* __restrict__ W1,
                                           __half* __restrict__ bufA,
                                           int N, int tile, char* smem) {
    constexpr int K = 128, KP = 136, NCT = 4;
    _Float16* WTh = (_Float16*)smem;
    _Float16* WTl = WTh + 64 * KP;

    for (int i = threadIdx.x; i < K * 64; i += 512) {
        int k = i >> 6, cc = i & 63;
        float w = W1[k * 64 + cc];
        _Float16 h = (_Float16)w;
        WTh[cc * KP + k] = h;
        WTl[cc * KP + k] = (_Float16)(w - (float)h);
    }
    __syncthreads();

    const int lane = threadIdx.x & 63;
    const int wv   = threadIdx.x >> 6;          // 0..7
    const int r    = lane & 15;
    const int q    = lane >> 4;
    int arow = tile * 128 + wv * 16 + r;
    if (arow > N - 1) arow = N - 1;

    f32x4 acc[NCT] = {};
#pragma unroll
    for (int kst = 0; kst < K; kst += 32) {
        half8 ah, al;
        const float* ap = x + (size_t)arow * K + kst + q * 8;
        float4 f0 = *(const float4*)ap;
        float4 f1 = *(const float4*)(ap + 4);
        float fs[8] = {f0.x, f0.y, f0.z, f0.w, f1.x, f1.y, f1.z, f1.w};
#pragma unroll
        for (int j = 0; j < 8; ++j) {
            _Float16 h = (_Float16)fs[j];
            ah[j] = h;
            al[j] = (_Float16)(fs[j] - (float)h);
        }
#pragma unroll
        for (int n = 0; n < NCT; ++n) {
            const int bo = (n * 16 + r) * KP + kst + q * 8;
            HV8 bh, bl;
            bh.u = *(const uint4*)(WTh + bo);
            bl.u = *(const uint4*)(WTl + bo);
            acc[n] = __builtin_amdgcn_mfma_f32_16x16x32_f16(ah, bh.h, acc[n], 0, 0, 0);
            acc[n] = __builtin_amdgcn_mfma_f32_16x16x32_f16(ah, bl.h, acc[n], 0, 0, 0);
            acc[n] = __builtin_amdgcn_mfma_f32_16x16x32_f16(al, bh.h, acc[n], 0, 0, 0);
        }
    }

    const int orow0 = tile * 128 + wv * 16 + q * 4;
#pragma unroll
    for (int n = 0; n < NCT; ++n) {
        const int col = n * 16 + r;
#pragma unroll
        for (int j = 0; j < 4; ++j) {
            const int row = orow0 + j;
            if (row >= N) break;
            bufA[(size_t)row * 64 + col] = __float2half(acc[n][j]);
        }
    }
}

// ---- D1: bucket_fill (blocks < EB) || gemm1 tiles [0,G1A) ------------------
__global__ __launch_bounds__(512) void fill_gemm1_kernel(
    const int* __restrict__ src, const int* __restrict__ dst,
    unsigned int* __restrict__ cntMat, unsigned int* __restrict__ bucketArr,
    const float* __restrict__ x, const float* __restrict__ W1,
    __half* __restrict__ bufA, int N, int E, int NB, int EB) {
    __shared__ __align__(16) char smem[38912];

    if ((int)blockIdx.x < EB) {
        // ---------------- fill ----------------
        unsigned int* ent = (unsigned int*)smem;          // 8192 entries, 32KB
        int* scn  = (int*)(smem + 32768);                 // [512]
        int* cl   = scn + 512;                            // [512]
        int* lcur = cl + 512;                             // [512]
        const int t = threadIdx.x;
        lcur[t] = 0;
        __syncthreads();

        const int base  = blockIdx.x * CHUNK;
        const int count = min(CHUNK, E - base);

        for (int i = t; i < count; i += 512)
            atomicAdd(&lcur[dst[base + i] >> BUCKET_BITS], 1);
        __syncthreads();

        int c = lcur[t];
        cl[t]  = c;
        scn[t] = c;
        __syncthreads();
        for (int off = 1; off < 512; off <<= 1) {
            int a = (t >= off) ? scn[t - off] : 0;
            __syncthreads();
            scn[t] += a;
            __syncthreads();
        }

        if (t < NB) cntMat[t * 128 + blockIdx.x] = (unsigned)min(c, SLOT);
        lcur[t] = scn[t] - c;                 // runStart (local cursor)
        __syncthreads();

        for (int i = t; i < count; i += 512) {
            const int d = dst[base + i];
            const int s = src[base + i];
            const int b = d >> BUCKET_BITS;
            const int p = atomicAdd(&lcur[b], 1);
            ent[p] = ((unsigned)(d & (BUCKET_NODES - 1)) << 24) | (unsigned)s;
        }
        __syncthreads();

        for (int j = t; j < count; j += 512) {
            int lo = 0, hi = 511;
            while (lo < hi) {
                int mid = (lo + hi) >> 1;
                if (scn[mid] > j) hi = mid; else lo = mid + 1;
            }
            const int off = j - (scn[lo] - cl[lo]);
            if (off < SLOT)
                bucketArr[lo * CAP + blockIdx.x * SLOT + off] = ent[j];
        }
    } else {
        gemm1_tile(x, W1, bufA, N, blockIdx.x - EB, smem);
    }
}

// ---- D2: node_sort (blocks < NB) || gemm1 tiles [G1A,782) ------------------
__global__ __launch_bounds__(512) void sort_gemm1_kernel(
    const unsigned int* __restrict__ cntMat, const unsigned int* __restrict__ bucketArr,
    unsigned int* __restrict__ nodeInfo, float* __restrict__ dinv,
    unsigned int* __restrict__ adj,
    const float* __restrict__ x, const float* __restrict__ W1,
    __half* __restrict__ bufA, int N, int NB, int EB) {
    __shared__ __align__(16) char smem[38912];

    if ((int)blockIdx.x < NB) {
        // ---------------- node_sort ----------------
        unsigned int* win = (unsigned int*)smem;          // CAP entries, 32KB
        int* cnt = (int*)(smem + 32768);                  // [256]
        int* scn = cnt + 256;                             // [256]
        int* cur = scn + 256;                             // [256]
        int* rc  = cur + 256;                             // [128]
        int* rs  = rc + 128;                              // [128]
        const int t = threadIdx.x;
        const int b = blockIdx.x;
        if (t < BUCKET_NODES) cnt[t] = 0;
        if (t < 128) rc[t] = (t < EB) ? (int)cntMat[b * 128 + t] : 0;
        __syncthreads();

        if (t < 128) rs[t] = rc[t];
        __syncthreads();
        for (int off = 1; off < 128; off <<= 1) {
            int a = 0;
            if (t < 128 && t >= off) a = rs[t - off];
            __syncthreads();
            if (t < 128) rs[t] += a;
            __syncthreads();
        }
        const int total = rs[127];

        for (int idx = t; idx < EB * SLOT; idx += 512) {
            const int eb  = idx >> 6;
            const int off = idx & (SLOT - 1);
            if (off < rc[eb]) {
                const unsigned e = bucketArr[b * CAP + idx];
                win[rs[eb] - rc[eb] + off] = e;
                atomicAdd(&cnt[e >> 24], 1);
            }
        }
        __syncthreads();

        if (t < BUCKET_NODES) scn[t] = cnt[t];
        __syncthreads();
        for (int off = 1; off < BUCKET_NODES; off <<= 1) {
            int a = 0;
            if (t < BUCKET_NODES && t >= off) a = scn[t - off];
            __syncthreads();
            if (t < BUCKET_NODES) scn[t] += a;
            __syncthreads();
        }
        if (t < BUCKET_NODES) {
            const int v    = cnt[t];
            const int excl = scn[t] - v;
            const int node = b * BUCKET_NODES + t;
            if (node < N) {
                nodeInfo[node] = ((unsigned)v << 22) | (unsigned)(b * CAP + excl);
                dinv[node]     = rsqrtf((float)(v + 1));
            }
            cur[t] = excl;
        }
        __syncthreads();

        for (int i = t; i < total; i += 512) {
            const unsigned entry = win[i];
            const int p = atomicAdd(&cur[entry >> 24], 1);
            adj[b * CAP + p] = entry & 0xFFFFFF;
        }
    } else {
        gemm1_tile(x, W1, bufA, N, blockIdx.x - NB + G1A, smem);
    }
}

// ---- MFMA GEMM (gemm2 / head): 512 threads = 8 waves x 16 rows = 128 rows --
template <int NOUT, int NCT, bool OHALF, bool SCALE, bool BIAS>
__global__ __launch_bounds__(512) void gemm_mfma(const __half* __restrict__ Ah,
                                                 const float* __restrict__ W,
                                                 const float* __restrict__ bias,
                                                 const float* __restrict__ dscale,
                                                 void* __restrict__ outv, int M) {
    constexpr int K = 64, KP = 72;
    __shared__ _Float16 WTh[64 * KP];
    __shared__ _Float16 WTl[64 * KP];

    for (int i = threadIdx.x; i < K * 64; i += 512) {
        int k = i >> 6, c = i & 63;
        float w = (NOUT == 64 || c < NOUT) ? W[k * NOUT + c] : 0.f;
        _Float16 h = (_Float16)w;
        WTh[c * KP + k] = h;
        WTl[c * KP + k] = (_Float16)(w - (float)h);
    }
    __syncthreads();

    const int lane = threadIdx.x & 63;
    const int wv   = threadIdx.x >> 6;          // 0..7
    const int r    = lane & 15;
    const int q    = lane >> 4;
    int arow = blockIdx.x * 128 + wv * 16 + r;
    if (arow > M - 1) arow = M - 1;

    f32x4 acc[NCT] = {};
#pragma unroll
    for (int kst = 0; kst < K; kst += 32) {
        HV8 v;
        v.u = *(const uint4*)(Ah + (size_t)arow * K + kst + q * 8);
#pragma unroll
        for (int n = 0; n < NCT; ++n) {
            const int bo = (n * 16 + r) * KP + kst + q * 8;
            HV8 bh, bl;
            bh.u = *(const uint4*)(WTh + bo);
            bl.u = *(const uint4*)(WTl + bo);
            acc[n] = __builtin_amdgcn_mfma_f32_16x16x32_f16(v.h, bh.h, acc[n], 0, 0, 0);
            acc[n] = __builtin_amdgcn_mfma_f32_16x16x32_f16(v.h, bl.h, acc[n], 0, 0, 0);
        }
    }

    const int orow0 = blockIdx.x * 128 + wv * 16 + q * 4;
#pragma unroll
    for (int n = 0; n < NCT; ++n) {
        const int col = n * 16 + r;
        float bb = 0.f;
        if (BIAS) bb = (col < NOUT) ? bias[col] : 0.f;
#pragma unroll
        for (int j = 0; j < 4; ++j) {
            const int row = orow0 + j;
            if (row >= M) break;
            const float sc = SCALE ? dscale[row] : 1.f;
            const float v2 = acc[n][j] * sc + bb;
            if (OHALF) {
                ((__half*)outv)[(size_t)row * NOUT + col] = __float2half(v2);
            } else if (col < NOUT) {
                ((float*)outv)[(size_t)row * NOUT + col] = v2;
            }
        }
    }
}

// ---- gather: eighth-wave; NBRSCALE=true applies dinv[s] per neighbor -------
template <bool NBRSCALE>
__global__ __launch_bounds__(256) void gather_kernel(const __half* __restrict__ h,
                                                     const unsigned int* __restrict__ nodeInfo,
                                                     const unsigned int* __restrict__ adj,
                                                     const float* __restrict__ dinv,
                                                     const float* __restrict__ bias,
                                                     __half* __restrict__ out, int N) {
    const int node = blockIdx.x * 32 + (threadIdx.x >> 3);
    const int l    = threadIdx.x & 7;
    if (node >= N) return;

    const unsigned info = nodeInfo[node];
    const int start = (int)(info & OFF_MASK);
    const int end   = start + (int)(info >> 22);
    const float di  = dinv[node];

    float acc[8];
    {
        H8 sv;
        sv.u = *(const uint4*)(h + (size_t)node * 64 + l * 8);
        const float self = NBRSCALE ? di : 1.f;
#pragma unroll
        for (int k = 0; k < 8; ++k) acc[k] = __half2float(sv.h[k]) * self;
    }

    for (int base = start; ; base += 8) {
        bool active = base < end;
        if (__ballot(active) == 0ull) break;
        const int m = active ? min(8, end - base) : 0;

        int s[8];
#pragma unroll
        for (int j = 0; j < 8; ++j) s[j] = (int)adj[base + j];

        float dv[8];
        if (NBRSCALE) {
#pragma unroll
            for (int j = 0; j < 8; ++j) dv[j] = (j < m) ? dinv[s[j]] : 0.f;
        }

        uint4 rv[8];
#pragma unroll
        for (int j = 0; j < 8; ++j)
            if (j < m) rv[j] = *(const uint4*)(h + (size_t)s[j] * 64 + l * 8);

#pragma unroll
        for (int j = 0; j < 8; ++j)
            if (j < m) {
                H8 tt;
                tt.u = rv[j];
                const float w = NBRSCALE ? dv[j] : 1.f;
#pragma unroll
                for (int k = 0; k < 8; ++k) acc[k] += __half2float(tt.h[k]) * w;
            }
    }

    const float4 b0 = *(const float4*)(bias + l * 8);
    const float4 b1 = *(const float4*)(bias + l * 8 + 4);
    const float bb[8] = {b0.x, b0.y, b0.z, b0.w, b1.x, b1.y, b1.z, b1.w};
    H8 ov;
#pragma unroll
    for (int k = 0; k < 8; ++k) {
        float v = acc[k] * di + bb[k];
        ov.h[k] = __float2half(v > 0.f ? v : 0.f);
    }
    *(uint4*)(out + (size_t)node * 64 + l * 8) = ov.u;
}

extern "C" void kernel_launch(void* const* d_in, const int* in_sizes, int n_in,
                              void* d_out, int out_size, void* d_ws, size_t ws_size,
                              hipStream_t stream) {
    const float* x  = (const float*)d_in[0];
    const int*   ei = (const int*)d_in[1];
    const float* W1 = (const float*)d_in[2];
    const float* b1 = (const float*)d_in[3];
    const float* W2 = (const float*)d_in[4];
    const float* b2 = (const float*)d_in[5];
    const float* Wc = (const float*)d_in[6];
    const float* bc = (const float*)d_in[7];

    const int N = in_sizes[0] / 128;   // 100000
    const int E = in_sizes[1] / 2;     // 1000000
    const int* src = ei;
    const int* dst = ei + E;

    const int NB = (N + BUCKET_NODES - 1) >> BUCKET_BITS;   // 391
    const int EB = (E + CHUNK - 1) / CHUNK;                  // 123

    char* w = (char*)d_ws;
    auto alloc = [&](size_t bytes) { char* p = w; w += (bytes + 255) & ~(size_t)255; return p; };
    unsigned int* cntMat    = (unsigned int*)alloc((size_t)NB * 128 * 4);
    unsigned int* bucketArr = (unsigned int*)alloc((size_t)NB * CAP * 4);
    unsigned int* nodeInfo  = (unsigned int*)alloc((size_t)N * 4);
    unsigned int* adj       = (unsigned int*)alloc((size_t)NB * CAP * 4);
    float*        dinv      = (float*)alloc((size_t)N * 4);
    __half*       bufA      = (__half*)alloc((size_t)N * 64 * 2);
    __half*       bufB      = (__half*)alloc((size_t)N * 64 * 2);
    __half*       bufC      = (__half*)alloc((size_t)N * 64 * 2);
    __half*       bufD      = (__half*)alloc((size_t)N * 64 * 2);

    const int nblkG = (N + 127) / 128;    // 782 gemm1 tiles total
    const int nblkV = (N + 31) / 32;      // 3125

    // D1: fill || gemm1 tiles [0, G1A)          (123 + 430 = 553 blocks)
    fill_gemm1_kernel<<<EB + G1A, dim3(512), 0, stream>>>(
        src, dst, cntMat, bucketArr, x, W1, bufA, N, E, NB, EB);

    // D2: sort || gemm1 tiles [G1A, 782)        (391 + 352 = 743 blocks)
    sort_gemm1_kernel<<<NB + (nblkG - G1A), dim3(512), 0, stream>>>(
        cntMat, bucketArr, nodeInfo, dinv, adj, x, W1, bufA, N, NB, EB);

    // D3: gather1 with per-neighbor dinv (bufA unscaled)
    gather_kernel<true><<<nblkV, dim3(256), 0, stream>>>(bufA, nodeInfo, adj, dinv, b1, bufB, N);

    // D4: gemm2: bufC = (bufB @ W2) * dinv
    gemm_mfma<64, 4, true, true, false><<<nblkG, dim3(512), 0, stream>>>(
        bufB, W2, nullptr, dinv, bufC, N);

    // D5: gather2 (pre-scaled form)
    gather_kernel<false><<<nblkV, dim3(256), 0, stream>>>(bufC, nodeInfo, adj, dinv, b2, bufD, N);

    // D6: head
    gemm_mfma<40, 3, false, false, true><<<nblkG, dim3(512), 0, stream>>>(
        bufD, Wc, bc, nullptr, d_out, N);
}